// Round 15
// baseline (190.375 us; speedup 1.0000x reference)
//
#include <hip/hip_runtime.h>
#include <hip/hip_bf16.h>

typedef unsigned short u16;
typedef unsigned int u32;
typedef unsigned long long u64;
typedef __attribute__((ext_vector_type(8))) short short8;   // 8 bf16 = 4 VGPR (MFMA A/B frag)
typedef __attribute__((ext_vector_type(4))) float floatx4;  // MFMA C/D frag
typedef const __attribute__((address_space(1))) void* gp_t; // global ptr for DMA
typedef __attribute__((address_space(3))) void* sp_t;       // LDS ptr for DMA

#define LOG2E 1.44269504088896f

static __device__ __forceinline__ float exp2_raw(float x) {
    float r; asm("v_exp_f32 %0, %1" : "=v"(r) : "v"(x)); return r;
}

static __device__ __forceinline__ u16 f2bf(float x) {
    __hip_bfloat16 h = __float2bfloat16(x);
    union { __hip_bfloat16 h; u16 u; } cv; cv.h = h; return cv.u;
}

// ---- prep1 (1216 blocks): ONLY what k_g1qk consumes --------------------------
// feats k-group (1024) | fc_w k-group (128) | effective q/k weights (64).
// The mask + fpw2 parts moved into k_g1qk to overlap with its compute.
__global__ __launch_bounds__(256)
void k_prep1(const float* __restrict__ feats, const float* __restrict__ fc_w,
             const float* __restrict__ fc_b,
             const float* __restrict__ q_w, const float* __restrict__ q_b,
             const float* __restrict__ k_w, const float* __restrict__ k_b,
             u16* __restrict__ feats2, u16* __restrict__ fcw2,
             u16* __restrict__ W, float* __restrict__ C) {
    __shared__ float shbuf[64 * 65];
    int id = blockIdx.x, t = threadIdx.x;
    if (id < 1024) {                        // feats -> feats2[d>>3][n][d&7]
        int n = id * 8 + (t >> 5), c = t & 31;
        const float* src = feats + (long)n * 256 + c * 8;
        float4 f0 = *(const float4*)src, f1 = *(const float4*)(src + 4);
        u16 tmp[8] = {f2bf(f0.x), f2bf(f0.y), f2bf(f0.z), f2bf(f0.w),
                      f2bf(f1.x), f2bf(f1.y), f2bf(f1.z), f2bf(f1.w)};
        *(int4*)&feats2[(long)c * 65536 + n * 8] = *(int4*)tmp;
    } else if (id < 1152) {                 // fc_w[256k][2048hd] -> fcw2[k>>3][hd][k&7]
        int b = id - 1024, bx = b & 31, by = b >> 5;
        float (*tt)[65] = (float(*)[65])shbuf;
        int c = t & 63, r0 = t >> 6;
        for (int rr = r0; rr < 64; rr += 4)
            tt[rr][c] = fc_w[(long)(by * 64 + rr) * 2048 + bx * 64 + c];
        __syncthreads();
        int hdl = t & 63;
        #pragma unroll
        for (int oo = 0; oo < 2; oo++) {
            int o = (t >> 6) + oo * 4;
            u16 tmp[8];
            #pragma unroll
            for (int e = 0; e < 8; e++) tmp[e] = f2bf(tt[o * 8 + e][hdl]);
            *(int4*)&fcw2[(long)(by * 8 + o) * 16384 + (bx * 64 + hdl) * 8] = *(int4*)tmp;
        }
    } else {                                // effective q/k weights
        int t2 = id - 1152, x = t2 & 15, dq = t2 >> 4;
        int h = x & 7, kind = x >> 3;
        const float* w = kind ? k_w : q_w;
        float* ws_ = shbuf;
        ws_[t] = w[t];
        __syncthreads();
        int wave = t >> 6, lane = t & 63;
        for (int j = 0; j < 16; j++) {
            int d = dq * 64 + wave * 16 + j;
            const float* row = fc_w + (long)d * 2048 + h * 256;
            float a = row[lane]        * ws_[lane]
                    + row[64 + lane]   * ws_[64 + lane]
                    + row[128 + lane]  * ws_[128 + lane]
                    + row[192 + lane]  * ws_[192 + lane];
            #pragma unroll
            for (int o = 1; o < 64; o <<= 1) a += __shfl_xor(a, o);
            if (lane == 0) W[(long)x * 256 + d] = f2bf(a);
        }
        if (dq == 0) {                      // C[x]: fully parallel reduction
            float cv = fc_b[h * 256 + t] * ws_[t];
            float* cred = shbuf + 256;
            cred[t] = cv;
            __syncthreads();
            if (t < 64) {
                float s = cred[t] + cred[t + 64] + cred[t + 128] + cred[t + 192];
                #pragma unroll
                for (int o = 1; o < 64; o <<= 1) s += __shfl_xor(s, o);
                if (t == 0) C[x] = s + (kind ? k_b[0] : q_b[0]);
            }
        }
    }
}

// ---- G1 (single-barrier DMA pipeline, LDS-transposed int4 epilogue)
// ---- + fused q/k MFMA + adj bitmask (HBM-bound, rides in G1's shadow)
// ---- + fp_w k-group. Grid dim3(64, 52):
// ----   y<16 G1 | y 16..17 qk | y 18..49 mask | y 50..51 fpw2.
__global__ __launch_bounds__(256)
void k_g1qk(const u16* __restrict__ fcw2, const u16* __restrict__ feats2,
            const float* __restrict__ bias, u16* __restrict__ V2,
            const u16* __restrict__ Wb, const float* __restrict__ C,
            float* __restrict__ qo, float* __restrict__ ko,
            const float* __restrict__ adj, u16* __restrict__ maskH,
            const float* __restrict__ fp_w, u16* __restrict__ fpw2) {
    __shared__ u16 smem[16896];             // As 2x4096 | Bs 2x4096 ; eb 128x132
    int tid = threadIdx.x, wave = tid >> 6, lane = tid & 63;
    int q = lane >> 4, n16 = lane & 15;

    if (blockIdx.y >= 18) {
        if (blockIdx.y < 50) {              // ---- adj -> bitmask (33.5 MB read) ----
            long m = (long)(blockIdx.y - 18) * 64 + blockIdx.x;
            long g = m * 256 + tid;
            const float4* ap = (const float4*)adj + g * 4;
            u32 mm = 0;
            #pragma unroll
            for (int w = 0; w < 4; w++) {
                float4 f = ap[w];
                mm |= (f.x > 0.f ? 1u : 0u) << (4 * w);
                mm |= (f.y > 0.f ? 1u : 0u) << (4 * w + 1);
                mm |= (f.z > 0.f ? 1u : 0u) << (4 * w + 2);
                mm |= (f.w > 0.f ? 1u : 0u) << (4 * w + 3);
            }
            maskH[g] = (u16)mm;
        } else {                            // ---- fp_w -> k-grouped fpw2 ----
            int b = (blockIdx.y - 50) * 64 + blockIdx.x;   // 0..127
            int bx = b & 3, by = b >> 2;
            float (*tt)[65] = (float(*)[65])smem;
            int c = tid & 63, r0 = tid >> 6;
            for (int rr = r0; rr < 64; rr += 4)
                tt[rr][c] = fp_w[(long)(by * 64 + rr) * 256 + bx * 64 + c];
            __syncthreads();
            int cl = tid & 63;
            #pragma unroll
            for (int oo = 0; oo < 2; oo++) {
                int o = (tid >> 6) + oo * 4;
                u16 tmp[8];
                #pragma unroll
                for (int e = 0; e < 8; e++) tmp[e] = f2bf(tt[o * 8 + e][cl]);
                *(int4*)&fpw2[(long)(by * 8 + o) * 2048 + (bx * 64 + cl) * 8] = *(int4*)tmp;
            }
        }
        return;
    }

    if (blockIdx.y >= 16) {                 // ---- q/k projection part ----
        int blk = (blockIdx.y - 16) * 64 + blockIdx.x;   // 0..127
        int rowBase = blk * 64 + wave * 16;
        floatx4 acc = {};
        #pragma unroll
        for (int k0 = 0; k0 < 256; k0 += 32) {
            short8 af = *(const short8*)&feats2[(long)((k0 >> 3) + q) * 65536
                                                + (rowBase + n16) * 8];
            short8 bf = *(const short8*)&Wb[n16 * 256 + k0 + q * 8];
            acc = __builtin_amdgcn_mfma_f32_16x16x32_bf16(af, bf, acc, 0, 0, 0);
        }
        float cc = C[n16];
        #pragma unroll
        for (int r = 0; r < 4; r++) {
            int gr = rowBase + q * 4 + r;
            int b = gr >> 10, nn = gr & 1023;
            float v = (acc[r] + cc) * LOG2E;        // pre-scale for v_exp in k_attn
            if (n16 < 8) qo[((b * 8 + n16) << 10) + nn] = v;
            else         ko[((b * 8 + (n16 - 8)) << 10) + nn] = v;
        }
        return;
    }

    int rowBase = blockIdx.y * 128;         // hd
    int colBase = blockIdx.x * 128;         // n
    int wr = wave >> 1, wc = wave & 1;
    floatx4 acc[4][4] = {};

    auto dma = [&](int k0, int p) {
        int kc = k0 >> 3;
        u16* Ab = smem + p * 4096;
        u16* Bb = smem + 8192 + p * 4096;
        #pragma unroll
        for (int r = 0; r < 2; r++) {
            __builtin_amdgcn_global_load_lds(
                (gp_t)&fcw2[(long)(kc + wave) * 16384 + (rowBase + r * 64 + lane) * 8],
                (sp_t)&Ab[(wave * 128 + r * 64 + lane) * 8], 16, 0, 0);
            __builtin_amdgcn_global_load_lds(
                (gp_t)&feats2[(long)(kc + wave) * 65536 + (colBase + r * 64 + lane) * 8],
                (sp_t)&Bb[(wave * 128 + r * 64 + lane) * 8], 16, 0, 0);
        }
    };

    dma(0, 0);
    __syncthreads();
    for (int k0 = 0; k0 < 256; k0 += 32) {
        int p = (k0 >> 5) & 1;
        u16* Ab = smem + p * 4096;
        u16* Bb = smem + 8192 + p * 4096;
        short8 af[4], bfr[4];
        #pragma unroll
        for (int i = 0; i < 4; i++)
            af[i] = *(short8*)&Ab[(q * 128 + wr * 64 + i * 16 + n16) * 8];
        #pragma unroll
        for (int i = 0; i < 4; i++)
            bfr[i] = *(short8*)&Bb[(q * 128 + wc * 64 + i * 16 + n16) * 8];
        if (k0 + 32 < 256) dma(k0 + 32, p ^ 1);
        #pragma unroll
        for (int mi = 0; mi < 4; mi++)
            #pragma unroll
            for (int ni = 0; ni < 4; ni++)
                acc[mi][ni] = __builtin_amdgcn_mfma_f32_16x16x32_bf16(
                    af[mi], bfr[ni], acc[mi][ni], 0, 0, 0);
        __syncthreads();
    }

    // ---- epilogue: stage bf16 tile [d_loc][nn_loc] in LDS (pitch 132),
    // ---- then coalesced int4 stores into k-grouped V2.
    u16* eb = smem;
    #pragma unroll
    for (int mi = 0; mi < 4; mi++) {
        #pragma unroll
        for (int r = 0; r < 4; r++) {
            int d_loc = wr * 64 + mi * 16 + q * 4 + r;
            float bv = bias[rowBase + d_loc];
            #pragma unroll
            for (int ni = 0; ni < 4; ni++) {
                int nn_loc = wc * 64 + ni * 16 + n16;
                eb[d_loc * 132 + nn_loc] = f2bf(acc[mi][ni][r] + bv);
            }
        }
    }
    __syncthreads();
    int hB = rowBase >> 8, dB = rowBase & 255;
    int bB = colBase >> 10, cB = (colBase & 1023) >> 3;
    long vbase = ((long)(bB * 8 + hB)) << 18;
    #pragma unroll
    for (int j = 0; j < 8; j++) {
        int idx = j * 256 + tid;
        int dl = idx & 127, c8 = idx >> 7;
        *(int4*)&V2[vbase + (long)(cB + c8) * 2048 + (dB + dl) * 8]
            = *(int4*)&eb[dl * 132 + c8 * 8];
    }
}

// -------- fused attention v8 (round-11 version, 51.5 us) --------
__global__ __launch_bounds__(512)
__attribute__((amdgpu_waves_per_eu(4)))
void k_attn(const u32* __restrict__ maskW, const float* __restrict__ qv,
            const float* __restrict__ kv, const u16* __restrict__ fpjT2,
            u16* __restrict__ outh2) {
    __shared__ u16 smem[26624];           // As 2x5120 | Bs 2x8192 ; eb 128x132
    __shared__ float qS[128], kS[1024], lsumS[512], rlS[128];

    int z = blockIdx.x;                   // bh  (XCD = z % 8)
    int b = z >> 3, h = z & 7;
    int i0 = blockIdx.y * 128;
    int tid = threadIdx.x;
    int wave = tid >> 6, lane = tid & 63;
    int wr = wave >> 2, wc = wave & 3;    // 2 x 4 wave grid
    int q  = lane >> 4, n16 = lane & 15;

    if (tid < 256) *(float4*)&kS[tid * 4] = *(const float4*)&kv[(z << 10) + tid * 4];
    if (tid >= 256 && tid < 384) qS[tid - 256] = qv[(z << 10) + i0 + (tid - 256)];

    floatx4 acc[4][4] = {};
    int ar = tid >> 2;                    // P row (0..127)
    int jq = (tid & 3) * 8;               // P j-offset within BK
    const u32* mrow = maskW + (((long)(b << 10) + i0 + ar) << 5);
    const u16* Vbase = fpjT2 + ((long)z << 18);
    float lsum = 0.f;

    auto dma_v = [&](int k0, int p) {
        u16* Bb = smem + 10240 + p * 8192;
        #pragma unroll
        for (int t = 0; t < 2; t++) {
            int s = wave * 2 + t;         // 16 segments of 1 KB
            __builtin_amdgcn_global_load_lds(
                (gp_t)&Vbase[((k0 >> 3) + (s >> 2)) * 2048 + ((s & 3) * 64 + lane) * 8],
                (sp_t)&Bb[((s >> 2) * 256 + (s & 3) * 64 + lane) * 8],
                16, 0, 0);
        }
    };

    __syncthreads();                      // qS/kS visible
    float qi = qS[ar];

    auto stage_p = [&](int p, u32 mw, float4 kA, float4 kB) {
        u16* Ab = smem + p * 5120;
        float kk[8] = {kA.x, kA.y, kA.z, kA.w, kB.x, kB.y, kB.z, kB.w};
        u32 pw[4];
        #pragma unroll
        for (int e2 = 0; e2 < 4; e2++) {
            float s0 = qi + kk[2 * e2];
            s0 = fmaxf(s0, 0.01f * s0);               // leaky (log2-domain)
            float p0 = ((mw >> (2 * e2)) & 1u) ? exp2_raw(s0) : 0.f;
            float s1 = qi + kk[2 * e2 + 1];
            s1 = fmaxf(s1, 0.01f * s1);
            float p1 = ((mw >> (2 * e2 + 1)) & 1u) ? exp2_raw(s1) : 0.f;
            lsum += p0 + p1;
            pw[e2] = __builtin_amdgcn_perm(__float_as_uint(p1), __float_as_uint(p0),
                                           0x07060302);   // {bf16(p1),bf16(p0)}
        }
        *(int4*)&Ab[ar * 40 + jq] = *(int4*)&pw[0];
    };

    {
        u32 mw0 = mrow[0] >> jq;
        float4 kA0 = *(const float4*)&kS[jq];
        float4 kB0 = *(const float4*)&kS[jq + 4];
        dma_v(0, 0);
        stage_p(0, mw0, kA0, kB0);
    }
    __syncthreads();                      // iter 0 staged (DMA drained here)

    for (int k0 = 0; k0 < 1024; k0 += 32) {
        int p = (k0 >> 5) & 1;
        u16* Ab = smem + p * 5120;
        u16* Bb = smem + 10240 + p * 8192;
        int kn = (k0 + 32 < 1024) ? k0 + 32 : 0;
        u32 mw = mrow[kn >> 5] >> jq;     // prefetch next mask + k values
        float4 kA = *(const float4*)&kS[kn + jq];
        float4 kB = *(const float4*)&kS[kn + jq + 4];
        short8 af[4], bfr[4];
        #pragma unroll
        for (int i = 0; i < 4; i++)
            af[i] = *(short8*)&Ab[(wr * 64 + i * 16 + n16) * 40 + q * 8];
        #pragma unroll
        for (int i = 0; i < 4; i++)
            bfr[i] = *(short8*)&Bb[(q * 256 + wc * 64 + i * 16 + n16) * 8];
        if (k0 + 32 < 1024) {
            dma_v(k0 + 32, p ^ 1);
            stage_p(p ^ 1, mw, kA, kB);
        }
        #pragma unroll
        for (int mi = 0; mi < 4; mi++)
            #pragma unroll
            for (int ni = 0; ni < 4; ni++)
                acc[mi][ni] = __builtin_amdgcn_mfma_f32_16x16x32_bf16(
                    af[mi], bfr[ni], acc[mi][ni], 0, 0, 0);
        __syncthreads();                  // next buffer staged + DMA drained
    }

    lsumS[tid] = lsum;
    __syncthreads();
    if (tid < 128) {
        float l = lsumS[4 * tid] + lsumS[4 * tid + 1] +
                  lsumS[4 * tid + 2] + lsumS[4 * tid + 3];
        rlS[tid] = l > 0.f ? 1.f / l : 0.f;
    }
    __syncthreads();

    // ---- epilogue: 2 column-halves through LDS (pitch 132), int4 stores ----
    u16* eb = smem;
    long rowG = (long)(b * 1024 + i0);
    #pragma unroll
    for (int hh = 0; hh < 2; hh++) {
        if ((wc >> 1) == hh) {
            #pragma unroll
            for (int mi = 0; mi < 4; mi++) {
                #pragma unroll
                for (int r = 0; r < 4; r++) {
                    int grow = wr * 64 + mi * 16 + q * 4 + r;
                    float s = rlS[grow];
                    #pragma unroll
                    for (int ni = 0; ni < 4; ni++) {
                        int col = (wc & 1) * 64 + ni * 16 + n16;
                        eb[grow * 132 + col] = f2bf(acc[mi][ni][r] * s);
                    }
                }
            }
        }
        __syncthreads();
        #pragma unroll
        for (int j = 0; j < 4; j++) {
            int idx = j * 512 + tid;
            int row = idx & 127, c8 = idx >> 7;      // c8 0..15
            int chunk = h * 32 + hh * 16 + c8;
            *(int4*)&outh2[((long)chunk << 16) + (rowG + row) * 8]
                = *(int4*)&eb[row * 132 + c8 * 8];
        }
        __syncthreads();
    }
}

// -------- G3 (round-11 shape): 64x32 tiles, BK=64, grid (128,8) = 4 blocks/CU;
// x=row-tile so the 8 col-siblings share an XCD (A2 L2-served). --------
__global__ __launch_bounds__(256)
void k_g3(const u16* __restrict__ A2,   // outh2 [256][8192][8]
          const u16* __restrict__ B2,   // fpw2  [256][256][8]
          const float* __restrict__ bias,
          const float* __restrict__ resid,
          float* __restrict__ out) {
    __shared__ u16 As[2][8 * 64 * 8];   // 8 KB / buf
    __shared__ u16 Bs[2][8 * 32 * 8];   // 4 KB / buf
    int rowBase = blockIdx.x * 64;
    int colBase = blockIdx.y * 32;
    int tid = threadIdx.x, wave = tid >> 6, lane = tid & 63;
    int q = lane >> 4, n16 = lane & 15;
    floatx4 acc[2] = {};

    auto dma = [&](int k0, int p) {
        int kc = k0 >> 3;
        #pragma unroll
        for (int t = 0; t < 2; t++) {
            int c = wave + t * 4;
            __builtin_amdgcn_global_load_lds(
                (gp_t)&A2[(long)(kc + c) * 65536 + (rowBase + lane) * 8],
                (sp_t)&As[p][(c * 64 + lane) * 8], 16, 0, 0);
        }
        __builtin_amdgcn_global_load_lds(
            (gp_t)&B2[(long)(kc + wave * 2 + (lane >> 5)) * 2048
                      + (colBase + (lane & 31)) * 8],
            (sp_t)&Bs[p][(wave * 64 + lane) * 8], 16, 0, 0);
    };

    dma(0, 0);
    __syncthreads();
    for (int k0 = 0; k0 < 2048; k0 += 64) {
        int p = (k0 >> 6) & 1;
        short8 af[2], bfr[2][2];
        #pragma unroll
        for (int kf = 0; kf < 2; kf++) {
            af[kf] = *(short8*)&As[p][((kf * 4 + q) * 64 + wave * 16 + n16) * 8];
            #pragma unroll
            for (int nf = 0; nf < 2; nf++)
                bfr[kf][nf] = *(short8*)&Bs[p][((kf * 4 + q) * 32 + nf * 16 + n16) * 8];
        }
        if (k0 + 64 < 2048) dma(k0 + 64, p ^ 1);
        #pragma unroll
        for (int kf = 0; kf < 2; kf++)
            #pragma unroll
            for (int nf = 0; nf < 2; nf++)
                acc[nf] = __builtin_amdgcn_mfma_f32_16x16x32_bf16(
                    af[kf], bfr[kf][nf], acc[nf], 0, 0, 0);
        __syncthreads();
    }

    #pragma unroll
    for (int nf = 0; nf < 2; nf++) {
        #pragma unroll
        for (int r = 0; r < 4; r++) {
            int grow = rowBase + wave * 16 + q * 4 + r;
            int gcol = colBase + nf * 16 + n16;
            float v = acc[nf][r] + bias[gcol] + resid[(long)grow * 256 + gcol];
            out[(long)grow * 256 + gcol] = 1.f / (1.f + __expf(-v));
        }
    }
}

extern "C" void kernel_launch(void* const* d_in, const int* in_sizes, int n_in,
                              void* d_out, int out_size, void* d_ws, size_t ws_size,
                              hipStream_t stream) {
    const float* feats = (const float*)d_in[0];
    const float* adj   = (const float*)d_in[1];
    const float* fc_w  = (const float*)d_in[2];
    const float* fc_b  = (const float*)d_in[3];
    const float* q_w   = (const float*)d_in[4];
    const float* q_b   = (const float*)d_in[5];
    const float* k_w   = (const float*)d_in[6];
    const float* k_b   = (const float*)d_in[7];
    const float* fp_w  = (const float*)d_in[8];
    const float* fp_b  = (const float*)d_in[9];

    char* ws = (char*)d_ws;
    u16*   feats2 = (u16*)ws;   ws += (size_t)2097152 * 2;   // [d>>3][n][d&7]
    u16*   fcw2   = (u16*)ws;   ws += (size_t)524288 * 2;    // [k>>3][hd][k&7]
    u16*   fpw2   = (u16*)ws;   ws += (size_t)524288 * 2;    // [k>>3][col][k&7]
    u16*   fpjT2  = (u16*)ws;   ws += (size_t)16777216 * 2;  // V2 [bh][n>>3][d][n&7]
    float* qv     = (float*)ws; ws += (size_t)65536 * 4;     // [b,h,n] (*log2e)
    float* kv     = (float*)ws; ws += (size_t)65536 * 4;
    u16*   outh2  = (u16*)ws;   ws += (size_t)16777216 * 2;  // [k>>3][row][k&7]
    u64*   maskB  = (u64*)ws;   ws += (size_t)131072 * 8;    // adj bits, 1 MB
    u16*   Weff   = (u16*)ws;   ws += (size_t)4096 * 2;      // [16][256] bf16
    float* Ceff   = (float*)ws; ws += (size_t)16 * 4;        // per-head consts

    // prep1: only g1qk's inputs (12 MB traffic)
    k_prep1<<<1216, 256, 0, stream>>>(feats, fc_w, fc_b, q_w, q_b, k_w, k_b,
                                      feats2, fcw2, Weff, Ceff);

    // G1 + qk + mask (rides in shadow) + fpw2
    k_g1qk<<<dim3(64, 52), 256, 0, stream>>>(fcw2, feats2, fc_b, fpjT2,
                                             Weff, Ceff, qv, kv,
                                             adj, (u16*)maskB, fp_w, fpw2);

    k_attn<<<dim3(64, 8), 512, 0, stream>>>((const u32*)maskB, qv, kv, fpjT2, outh2);

    k_g3<<<dim3(128, 8), 256, 0, stream>>>(outh2, fpw2, fp_b, feats, (float*)d_out);
}

// Round 16
// 186.556 us; speedup vs baseline: 1.0205x; 1.0205x over previous
//
#include <hip/hip_runtime.h>
#include <hip/hip_bf16.h>

typedef unsigned short u16;
typedef unsigned int u32;
typedef unsigned long long u64;
typedef __attribute__((ext_vector_type(8))) short short8;   // 8 bf16 = 4 VGPR (MFMA A/B frag)
typedef __attribute__((ext_vector_type(4))) float floatx4;  // MFMA C/D frag
typedef const __attribute__((address_space(1))) void* gp_t; // global ptr for DMA
typedef __attribute__((address_space(3))) void* sp_t;       // LDS ptr for DMA

#define LOG2E 1.44269504088896f

static __device__ __forceinline__ float exp2_raw(float x) {
    float r; asm("v_exp_f32 %0, %1" : "=v"(r) : "v"(x)); return r;
}

static __device__ __forceinline__ u16 f2bf(float x) {
    __hip_bfloat16 h = __float2bfloat16(x);
    union { __hip_bfloat16 h; u16 u; } cv; cv.h = h; return cv.u;
}
static __device__ __forceinline__ float bf2f(u16 u) {
    union { u16 u; __hip_bfloat16 h; } cv; cv.u = u;
    return __bfloat162float(cv.h);
}

// ---- fused prep (3392 blocks): adj bitmask | feats k-group | fc_w k-group
// ---- | fp_w k-group | effective q/k weights (coalesced + parallel C).
__global__ __launch_bounds__(256)
void k_prepall(const float* __restrict__ feats, const float* __restrict__ adj,
               const float* __restrict__ fc_w, const float* __restrict__ fc_b,
               const float* __restrict__ q_w, const float* __restrict__ q_b,
               const float* __restrict__ k_w, const float* __restrict__ k_b,
               const float* __restrict__ fp_w,
               u16* __restrict__ feats2, u16* __restrict__ maskH,
               u16* __restrict__ fcw2, u16* __restrict__ fpw2,
               u16* __restrict__ W, float* __restrict__ C) {
    __shared__ float shbuf[64 * 65];
    int id = blockIdx.x, t = threadIdx.x;
    if (id < 2048) {                        // adj -> bits, 16 elems/thread
        long g = (long)id * 256 + t;
        const float4* ap = (const float4*)adj + g * 4;
        u32 mm = 0;
        #pragma unroll
        for (int w = 0; w < 4; w++) {
            float4 f = ap[w];
            mm |= (f.x > 0.f ? 1u : 0u) << (4 * w);
            mm |= (f.y > 0.f ? 1u : 0u) << (4 * w + 1);
            mm |= (f.z > 0.f ? 1u : 0u) << (4 * w + 2);
            mm |= (f.w > 0.f ? 1u : 0u) << (4 * w + 3);
        }
        maskH[g] = (u16)mm;
    } else if (id < 3072) {                 // feats -> feats2[d>>3][n][d&7]
        int n = (id - 2048) * 8 + (t >> 5), c = t & 31;
        const float* src = feats + (long)n * 256 + c * 8;
        float4 f0 = *(const float4*)src, f1 = *(const float4*)(src + 4);
        u16 tmp[8] = {f2bf(f0.x), f2bf(f0.y), f2bf(f0.z), f2bf(f0.w),
                      f2bf(f1.x), f2bf(f1.y), f2bf(f1.z), f2bf(f1.w)};
        *(int4*)&feats2[(long)c * 65536 + n * 8] = *(int4*)tmp;
    } else if (id < 3200) {                 // fc_w[256k][2048hd] -> fcw2[k>>3][hd][k&7]
        int b = id - 3072, bx = b & 31, by = b >> 5;
        float (*tt)[65] = (float(*)[65])shbuf;
        int c = t & 63, r0 = t >> 6;
        for (int rr = r0; rr < 64; rr += 4)
            tt[rr][c] = fc_w[(long)(by * 64 + rr) * 2048 + bx * 64 + c];
        __syncthreads();
        int hdl = t & 63;
        #pragma unroll
        for (int oo = 0; oo < 2; oo++) {
            int o = (t >> 6) + oo * 4;
            u16 tmp[8];
            #pragma unroll
            for (int e = 0; e < 8; e++) tmp[e] = f2bf(tt[o * 8 + e][hdl]);
            *(int4*)&fcw2[(long)(by * 8 + o) * 16384 + (bx * 64 + hdl) * 8] = *(int4*)tmp;
        }
    } else if (id < 3328) {                 // fp_w[2048k][256c] -> fpw2[k>>3][c][k&7]
        int b = id - 3200, bx = b & 3, by = b >> 2;
        float (*tt)[65] = (float(*)[65])shbuf;
        int c = t & 63, r0 = t >> 6;
        for (int rr = r0; rr < 64; rr += 4)
            tt[rr][c] = fp_w[(long)(by * 64 + rr) * 256 + bx * 64 + c];
        __syncthreads();
        int cl = t & 63;
        #pragma unroll
        for (int oo = 0; oo < 2; oo++) {
            int o = (t >> 6) + oo * 4;
            u16 tmp[8];
            #pragma unroll
            for (int e = 0; e < 8; e++) tmp[e] = f2bf(tt[o * 8 + e][cl]);
            *(int4*)&fpw2[(long)(by * 8 + o) * 2048 + (bx * 64 + cl) * 8] = *(int4*)tmp;
        }
    } else {                                // effective q/k weights
        int t2 = id - 3328, x = t2 & 15, dq = t2 >> 4;
        int h = x & 7, kind = x >> 3;
        const float* w = kind ? k_w : q_w;
        float* ws_ = shbuf;
        ws_[t] = w[t];
        __syncthreads();
        int wave = t >> 6, lane = t & 63;
        // wave-per-d: lanes span the 256-wide reduction (coalesced 256-B loads)
        for (int j = 0; j < 16; j++) {
            int d = dq * 64 + wave * 16 + j;
            const float* row = fc_w + (long)d * 2048 + h * 256;
            float a = row[lane]        * ws_[lane]
                    + row[64 + lane]   * ws_[64 + lane]
                    + row[128 + lane]  * ws_[128 + lane]
                    + row[192 + lane]  * ws_[192 + lane];
            #pragma unroll
            for (int o = 1; o < 64; o <<= 1) a += __shfl_xor(a, o);
            if (lane == 0) W[(long)x * 256 + d] = f2bf(a);
        }
        if (dq == 0) {                      // C[x]: fully parallel reduction
            float cv = fc_b[h * 256 + t] * ws_[t];
            float* cred = shbuf + 256;
            cred[t] = cv;
            __syncthreads();
            if (t < 64) {
                float s = cred[t] + cred[t + 64] + cred[t + 128] + cred[t + 192];
                #pragma unroll
                for (int o = 1; o < 64; o <<= 1) s += __shfl_xor(s, o);
                if (t == 0) C[x] = s + (kind ? k_b[0] : q_b[0]);
            }
        }
    }
}

// ---- G1 (single-barrier DMA pipeline, LDS-transposed int4 epilogue)
// ---- + fused q/k MFMA blocks (outputs pre-scaled by log2 e) ----
__global__ __launch_bounds__(256)
void k_g1qk(const u16* __restrict__ fcw2, const u16* __restrict__ feats2,
            const float* __restrict__ bias, u16* __restrict__ V2,
            const u16* __restrict__ Wb, const float* __restrict__ C,
            float* __restrict__ qo, float* __restrict__ ko) {
    __shared__ u16 smem[16896];             // As 2x4096 | Bs 2x4096 ; eb 128x132
    int tid = threadIdx.x, wave = tid >> 6, lane = tid & 63;
    int q = lane >> 4, n16 = lane & 15;

    if (blockIdx.y >= 16) {                 // ---- q/k projection part ----
        int blk = (blockIdx.y - 16) * 64 + blockIdx.x;   // 0..127
        int rowBase = blk * 64 + wave * 16;
        floatx4 acc = {};
        #pragma unroll
        for (int k0 = 0; k0 < 256; k0 += 32) {
            short8 af = *(const short8*)&feats2[(long)((k0 >> 3) + q) * 65536
                                                + (rowBase + n16) * 8];
            short8 bf = *(const short8*)&Wb[n16 * 256 + k0 + q * 8];
            acc = __builtin_amdgcn_mfma_f32_16x16x32_bf16(af, bf, acc, 0, 0, 0);
        }
        float cc = C[n16];
        #pragma unroll
        for (int r = 0; r < 4; r++) {
            int gr = rowBase + q * 4 + r;
            int b = gr >> 10, nn = gr & 1023;
            float v = (acc[r] + cc) * LOG2E;        // pre-scale for v_exp in k_attn
            if (n16 < 8) qo[((b * 8 + n16) << 10) + nn] = v;
            else         ko[((b * 8 + (n16 - 8)) << 10) + nn] = v;
        }
        return;
    }

    int rowBase = blockIdx.y * 128;         // hd
    int colBase = blockIdx.x * 128;         // n
    int wr = wave >> 1, wc = wave & 1;
    floatx4 acc[4][4] = {};

    auto dma = [&](int k0, int p) {
        int kc = k0 >> 3;
        u16* Ab = smem + p * 4096;
        u16* Bb = smem + 8192 + p * 4096;
        #pragma unroll
        for (int r = 0; r < 2; r++) {
            __builtin_amdgcn_global_load_lds(
                (gp_t)&fcw2[(long)(kc + wave) * 16384 + (rowBase + r * 64 + lane) * 8],
                (sp_t)&Ab[(wave * 128 + r * 64 + lane) * 8], 16, 0, 0);
            __builtin_amdgcn_global_load_lds(
                (gp_t)&feats2[(long)(kc + wave) * 65536 + (colBase + r * 64 + lane) * 8],
                (sp_t)&Bb[(wave * 128 + r * 64 + lane) * 8], 16, 0, 0);
        }
    };

    dma(0, 0);
    __syncthreads();
    for (int k0 = 0; k0 < 256; k0 += 32) {
        int p = (k0 >> 5) & 1;
        u16* Ab = smem + p * 4096;
        u16* Bb = smem + 8192 + p * 4096;
        short8 af[4], bfr[4];
        #pragma unroll
        for (int i = 0; i < 4; i++)
            af[i] = *(short8*)&Ab[(q * 128 + wr * 64 + i * 16 + n16) * 8];
        #pragma unroll
        for (int i = 0; i < 4; i++)
            bfr[i] = *(short8*)&Bb[(q * 128 + wc * 64 + i * 16 + n16) * 8];
        if (k0 + 32 < 256) dma(k0 + 32, p ^ 1);
        #pragma unroll
        for (int mi = 0; mi < 4; mi++)
            #pragma unroll
            for (int ni = 0; ni < 4; ni++)
                acc[mi][ni] = __builtin_amdgcn_mfma_f32_16x16x32_bf16(
                    af[mi], bfr[ni], acc[mi][ni], 0, 0, 0);
        __syncthreads();
    }

    // ---- epilogue: stage bf16 tile [d_loc][nn_loc] in LDS (pitch 132),
    // ---- then coalesced int4 stores into k-grouped V2.
    u16* eb = smem;
    #pragma unroll
    for (int mi = 0; mi < 4; mi++) {
        #pragma unroll
        for (int r = 0; r < 4; r++) {
            int d_loc = wr * 64 + mi * 16 + q * 4 + r;
            float bv = bias[rowBase + d_loc];
            #pragma unroll
            for (int ni = 0; ni < 4; ni++) {
                int nn_loc = wc * 64 + ni * 16 + n16;
                eb[d_loc * 132 + nn_loc] = f2bf(acc[mi][ni][r] + bv);
            }
        }
    }
    __syncthreads();
    int hB = rowBase >> 8, dB = rowBase & 255;
    int bB = colBase >> 10, cB = (colBase & 1023) >> 3;
    long vbase = ((long)(bB * 8 + hB)) << 18;
    #pragma unroll
    for (int j = 0; j < 8; j++) {
        int idx = j * 256 + tid;
        int dl = idx & 127, c8 = idx >> 7;
        *(int4*)&V2[vbase + (long)(cB + c8) * 2048 + (dB + dl) * 8]
            = *(int4*)&eb[dl * 132 + c8 * 8];
    }
}

// -------- fused attention v8 (round-11 version, 51.5 us) --------
__global__ __launch_bounds__(512)
__attribute__((amdgpu_waves_per_eu(4)))
void k_attn(const u32* __restrict__ maskW, const float* __restrict__ qv,
            const float* __restrict__ kv, const u16* __restrict__ fpjT2,
            u16* __restrict__ outh2) {
    __shared__ u16 smem[26624];           // As 2x5120 | Bs 2x8192 ; eb 128x132
    __shared__ float qS[128], kS[1024], lsumS[512], rlS[128];

    int z = blockIdx.x;                   // bh  (XCD = z % 8)
    int b = z >> 3, h = z & 7;
    int i0 = blockIdx.y * 128;
    int tid = threadIdx.x;
    int wave = tid >> 6, lane = tid & 63;
    int wr = wave >> 2, wc = wave & 3;    // 2 x 4 wave grid
    int q  = lane >> 4, n16 = lane & 15;

    if (tid < 256) *(float4*)&kS[tid * 4] = *(const float4*)&kv[(z << 10) + tid * 4];
    if (tid >= 256 && tid < 384) qS[tid - 256] = qv[(z << 10) + i0 + (tid - 256)];

    floatx4 acc[4][4] = {};
    int ar = tid >> 2;                    // P row (0..127)
    int jq = (tid & 3) * 8;               // P j-offset within BK
    const u32* mrow = maskW + (((long)(b << 10) + i0 + ar) << 5);
    const u16* Vbase = fpjT2 + ((long)z << 18);
    float lsum = 0.f;

    auto dma_v = [&](int k0, int p) {
        u16* Bb = smem + 10240 + p * 8192;
        #pragma unroll
        for (int t = 0; t < 2; t++) {
            int s = wave * 2 + t;         // 16 segments of 1 KB
            __builtin_amdgcn_global_load_lds(
                (gp_t)&Vbase[((k0 >> 3) + (s >> 2)) * 2048 + ((s & 3) * 64 + lane) * 8],
                (sp_t)&Bb[((s >> 2) * 256 + (s & 3) * 64 + lane) * 8],
                16, 0, 0);
        }
    };

    __syncthreads();                      // qS/kS visible
    float qi = qS[ar];

    auto stage_p = [&](int p, u32 mw, float4 kA, float4 kB) {
        u16* Ab = smem + p * 5120;
        float kk[8] = {kA.x, kA.y, kA.z, kA.w, kB.x, kB.y, kB.z, kB.w};
        u32 pw[4];
        #pragma unroll
        for (int e2 = 0; e2 < 4; e2++) {
            float s0 = qi + kk[2 * e2];
            s0 = fmaxf(s0, 0.01f * s0);               // leaky (log2-domain)
            float p0 = ((mw >> (2 * e2)) & 1u) ? exp2_raw(s0) : 0.f;
            float s1 = qi + kk[2 * e2 + 1];
            s1 = fmaxf(s1, 0.01f * s1);
            float p1 = ((mw >> (2 * e2 + 1)) & 1u) ? exp2_raw(s1) : 0.f;
            lsum += p0 + p1;
            pw[e2] = __builtin_amdgcn_perm(__float_as_uint(p1), __float_as_uint(p0),
                                           0x07060302);   // {bf16(p1),bf16(p0)}
        }
        *(int4*)&Ab[ar * 40 + jq] = *(int4*)&pw[0];
    };

    {
        u32 mw0 = mrow[0] >> jq;
        float4 kA0 = *(const float4*)&kS[jq];
        float4 kB0 = *(const float4*)&kS[jq + 4];
        dma_v(0, 0);
        stage_p(0, mw0, kA0, kB0);
    }
    __syncthreads();                      // iter 0 staged (DMA drained here)

    for (int k0 = 0; k0 < 1024; k0 += 32) {
        int p = (k0 >> 5) & 1;
        u16* Ab = smem + p * 5120;
        u16* Bb = smem + 10240 + p * 8192;
        int kn = (k0 + 32 < 1024) ? k0 + 32 : 0;
        u32 mw = mrow[kn >> 5] >> jq;     // prefetch next mask + k values
        float4 kA = *(const float4*)&kS[kn + jq];
        float4 kB = *(const float4*)&kS[kn + jq + 4];
        short8 af[4], bfr[4];
        #pragma unroll
        for (int i = 0; i < 4; i++)
            af[i] = *(short8*)&Ab[(wr * 64 + i * 16 + n16) * 40 + q * 8];
        #pragma unroll
        for (int i = 0; i < 4; i++)
            bfr[i] = *(short8*)&Bb[(q * 256 + wc * 64 + i * 16 + n16) * 8];
        if (k0 + 32 < 1024) {
            dma_v(k0 + 32, p ^ 1);
            stage_p(p ^ 1, mw, kA, kB);
        }
        #pragma unroll
        for (int mi = 0; mi < 4; mi++)
            #pragma unroll
            for (int ni = 0; ni < 4; ni++)
                acc[mi][ni] = __builtin_amdgcn_mfma_f32_16x16x32_bf16(
                    af[mi], bfr[ni], acc[mi][ni], 0, 0, 0);
        __syncthreads();                  // next buffer staged + DMA drained
    }

    lsumS[tid] = lsum;
    __syncthreads();
    if (tid < 128) {
        float l = lsumS[4 * tid] + lsumS[4 * tid + 1] +
                  lsumS[4 * tid + 2] + lsumS[4 * tid + 3];
        rlS[tid] = l > 0.f ? 1.f / l : 0.f;
    }
    __syncthreads();

    // ---- epilogue: 2 column-halves through LDS (pitch 132), int4 stores ----
    u16* eb = smem;
    long rowG = (long)(b * 1024 + i0);
    #pragma unroll
    for (int hh = 0; hh < 2; hh++) {
        if ((wc >> 1) == hh) {
            #pragma unroll
            for (int mi = 0; mi < 4; mi++) {
                #pragma unroll
                for (int r = 0; r < 4; r++) {
                    int grow = wr * 64 + mi * 16 + q * 4 + r;
                    float s = rlS[grow];
                    #pragma unroll
                    for (int ni = 0; ni < 4; ni++) {
                        int col = (wc & 1) * 64 + ni * 16 + n16;
                        eb[grow * 132 + col] = f2bf(acc[mi][ni][r] * s);
                    }
                }
            }
        }
        __syncthreads();
        #pragma unroll
        for (int j = 0; j < 4; j++) {
            int idx = j * 512 + tid;
            int row = idx & 127, c8 = idx >> 7;      // c8 0..15
            int chunk = h * 32 + hh * 16 + c8;
            *(int4*)&outh2[((long)chunk << 16) + (rowG + row) * 8]
                = *(int4*)&eb[row * 132 + c8 * 8];
        }
        __syncthreads();
    }
}

// -------- G3: 64x32 tiles, BK=64, grid (128,8); residual read from bf16
// feats2 (4 MB, DMA-staged once per block) instead of fp32 feats (33.5 MB):
// saves ~30 MB HBM on the last kernel. --------
__global__ __launch_bounds__(256)
void k_g3(const u16* __restrict__ A2,   // outh2 [256][8192][8]
          const u16* __restrict__ B2,   // fpw2  [256][256][8]
          const float* __restrict__ bias,
          const u16* __restrict__ resid2,  // feats2 [d>>3][n][d&7]
          float* __restrict__ out) {
    __shared__ u16 As[2][8 * 64 * 8];   // 8 KB / buf
    __shared__ u16 Bs[2][8 * 32 * 8];   // 4 KB / buf
    __shared__ u16 Rs[4 * 64 * 8];      // resid tile: 4 chunks x 64 rows x 8
    int rowBase = blockIdx.x * 64;
    int colBase = blockIdx.y * 32;
    int tid = threadIdx.x, wave = tid >> 6, lane = tid & 63;
    int q = lane >> 4, n16 = lane & 15;
    floatx4 acc[2] = {};

    auto dma = [&](int k0, int p) {
        int kc = k0 >> 3;
        #pragma unroll
        for (int t = 0; t < 2; t++) {
            int c = wave + t * 4;
            __builtin_amdgcn_global_load_lds(
                (gp_t)&A2[(long)(kc + c) * 65536 + (rowBase + lane) * 8],
                (sp_t)&As[p][(c * 64 + lane) * 8], 16, 0, 0);
        }
        __builtin_amdgcn_global_load_lds(
            (gp_t)&B2[(long)(kc + wave * 2 + (lane >> 5)) * 2048
                      + (colBase + (lane & 31)) * 8],
            (sp_t)&Bs[p][(wave * 64 + lane) * 8], 16, 0, 0);
    };

    // resid tile: 4 feats2-chunks covering cols [colBase, colBase+32)
    if (wave < 4)
        __builtin_amdgcn_global_load_lds(
            (gp_t)&resid2[(long)((colBase >> 3) + wave) * 65536 + (rowBase + lane) * 8],
            (sp_t)&Rs[(wave * 64 + lane) * 8], 16, 0, 0);
    dma(0, 0);
    __syncthreads();
    for (int k0 = 0; k0 < 2048; k0 += 64) {
        int p = (k0 >> 6) & 1;
        short8 af[2], bfr[2][2];
        #pragma unroll
        for (int kf = 0; kf < 2; kf++) {
            af[kf] = *(short8*)&As[p][((kf * 4 + q) * 64 + wave * 16 + n16) * 8];
            #pragma unroll
            for (int nf = 0; nf < 2; nf++)
                bfr[kf][nf] = *(short8*)&Bs[p][((kf * 4 + q) * 32 + nf * 16 + n16) * 8];
        }
        if (k0 + 64 < 2048) dma(k0 + 64, p ^ 1);
        #pragma unroll
        for (int kf = 0; kf < 2; kf++)
            #pragma unroll
            for (int nf = 0; nf < 2; nf++)
                acc[nf] = __builtin_amdgcn_mfma_f32_16x16x32_bf16(
                    af[kf], bfr[kf][nf], acc[nf], 0, 0, 0);
        __syncthreads();
    }

    #pragma unroll
    for (int nf = 0; nf < 2; nf++) {
        int cloc = nf * 16 + n16;               // 0..31
        int cc = cloc >> 3, ce = cloc & 7;
        float bv = bias[colBase + cloc];
        #pragma unroll
        for (int r = 0; r < 4; r++) {
            int rloc = wave * 16 + q * 4 + r;   // 0..63
            float rv = bf2f(Rs[(cc * 64 + rloc) * 8 + ce]);
            float v = acc[nf][r] + bv + rv;
            out[(long)(rowBase + rloc) * 256 + colBase + cloc]
                = 1.f / (1.f + __expf(-v));
        }
    }
}

extern "C" void kernel_launch(void* const* d_in, const int* in_sizes, int n_in,
                              void* d_out, int out_size, void* d_ws, size_t ws_size,
                              hipStream_t stream) {
    const float* feats = (const float*)d_in[0];
    const float* adj   = (const float*)d_in[1];
    const float* fc_w  = (const float*)d_in[2];
    const float* fc_b  = (const float*)d_in[3];
    const float* q_w   = (const float*)d_in[4];
    const float* q_b   = (const float*)d_in[5];
    const float* k_w   = (const float*)d_in[6];
    const float* k_b   = (const float*)d_in[7];
    const float* fp_w  = (const float*)d_in[8];
    const float* fp_b  = (const float*)d_in[9];

    char* ws = (char*)d_ws;
    u16*   feats2 = (u16*)ws;   ws += (size_t)2097152 * 2;   // [d>>3][n][d&7]
    u16*   fcw2   = (u16*)ws;   ws += (size_t)524288 * 2;    // [k>>3][hd][k&7]
    u16*   fpw2   = (u16*)ws;   ws += (size_t)524288 * 2;    // [k>>3][col][k&7]
    u16*   fpjT2  = (u16*)ws;   ws += (size_t)16777216 * 2;  // V2 [bh][n>>3][d][n&7]
    float* qv     = (float*)ws; ws += (size_t)65536 * 4;     // [b,h,n] (*log2e)
    float* kv     = (float*)ws; ws += (size_t)65536 * 4;
    u16*   outh2  = (u16*)ws;   ws += (size_t)16777216 * 2;  // [k>>3][row][k&7]
    u64*   maskB  = (u64*)ws;   ws += (size_t)131072 * 8;    // adj bits, 1 MB
    u16*   Weff   = (u16*)ws;   ws += (size_t)4096 * 2;      // [16][256] bf16
    float* Ceff   = (float*)ws; ws += (size_t)16 * 4;        // per-head consts

    k_prepall<<<3392, 256, 0, stream>>>(feats, adj, fc_w, fc_b, q_w, q_b,
                                        k_w, k_b, fp_w,
                                        feats2, (u16*)maskB, fcw2, fpw2, Weff, Ceff);

    k_g1qk<<<dim3(64, 18), 256, 0, stream>>>(fcw2, feats2, fc_b, fpjT2,
                                             Weff, Ceff, qv, kv);

    k_attn<<<dim3(64, 8), 512, 0, stream>>>((const u32*)maskB, qv, kv, fpjT2, outh2);

    k_g3<<<dim3(128, 8), 256, 0, stream>>>(outh2, fpw2, fp_b, feats2, (float*)d_out);
}